// Round 2
// baseline (318.883 us; speedup 1.0000x reference)
//
#include <hip/hip_runtime.h>

// QuantileLoss: mean over [ (p0-t0)^2, (p1-t1)^2, (p2-t2)^2, lower, upper ]
//   lower = p3>p2 ? (p4-t2)*4 : (p3>0.95*t2 ? 0 : (p3-0.95*t2)^2)
//   upper = p4<p2 ? (p4-t2)*4 : (p4<1.05*t2 ? 0 : (p4-1.05*t2)^2)
//
// R1 evidence: row-contiguous per-lane loads were transaction-bound (61 us
// even when fully L3-resident). Fix: coalesced float4 staging into LDS,
// then 1 row/thread readback at odd stride (5/3 floats -> 2-way bank alias,
// free on gfx950 per m136).

#define BLOCK 256
#define TILE  256   // rows per block; TILE*5 floats = 320 float4, TILE*3 = 192 float4

__device__ __forceinline__ float row_loss(float p0, float p1, float p2,
                                          float p3, float p4,
                                          float t0, float t1, float t2) {
    float d0 = p0 - t0, d1 = p1 - t1, d2 = p2 - t2;
    float acc = d0 * d0 + d1 * d1 + d2 * d2;
    float tl = t2 * 0.95f;
    float tu = t2 * 1.05f;
    float pen = (p4 - t2) * 4.0f;
    float dl = p3 - tl;
    float du = p4 - tu;
    float lower = (p3 > p2) ? pen : ((p3 > tl) ? 0.0f : dl * dl);
    float upper = (p4 < p2) ? pen : ((p4 < tu) ? 0.0f : du * du);
    return acc + lower + upper;
}

__global__ __launch_bounds__(BLOCK) void ql_main(const float* __restrict__ preds,
                                                 const float* __restrict__ target,
                                                 double* __restrict__ ws,
                                                 long rows) {
    __shared__ float sp[TILE * 5];   // 5 KB
    __shared__ float st[TILE * 3];   // 3 KB
    __shared__ double wsum[BLOCK / 64];

    const int t = threadIdx.x;
    const long row0 = (long)blockIdx.x * TILE;
    float loss = 0.0f;

    if (row0 + TILE <= rows) {
        // ---- coalesced staging: 320 preds float4 + 192 target float4 = 512 = 2/thread
        const float4* pbase = (const float4*)(preds + row0 * 5);  // row0*5 % 4 == 0
        const float4* tbase = (const float4*)(target + row0 * 3); // row0*3 % 4 == 0
        float4* sp4 = (float4*)sp;
        float4* st4 = (float4*)st;

        // round 1: k = t in [0,256) -> all preds
        sp4[t] = pbase[t];
        // round 2: k = t+256 in [256,512)
        int k2 = t + 256;
        if (k2 < TILE * 5 / 4) {          // [256,320): preds (wave 0)
            sp4[k2] = pbase[k2];
        } else {                          // [320,512) -> target [0,192) (waves 1-3)
            int m = k2 - TILE * 5 / 4;
            st4[m] = tbase[m];
        }
        __syncthreads();

        // ---- readback: 1 row per thread, stride 5 / stride 3 (odd -> conflict-free)
        loss = row_loss(sp[5 * t + 0], sp[5 * t + 1], sp[5 * t + 2],
                        sp[5 * t + 3], sp[5 * t + 4],
                        st[3 * t + 0], st[3 * t + 1], st[3 * t + 2]);
    } else {
        // tail tile (not hit for N=4194304, kept for generality)
        long r = row0 + t;
        if (r < rows) {
            const float* p = preds + r * 5;
            const float* tg = target + r * 3;
            loss = row_loss(p[0], p[1], p[2], p[3], p[4], tg[0], tg[1], tg[2]);
        }
        __syncthreads();
    }

    // ---- wave reduction in double, then cross-wave via LDS, one atomic/block
    double dacc = (double)loss;
#pragma unroll
    for (int off = 32; off > 0; off >>= 1)
        dacc += __shfl_down(dacc, off, 64);

    int lane = t & 63;
    int wave = t >> 6;
    if (lane == 0) wsum[wave] = dacc;
    __syncthreads();

    if (t == 0) {
        double b = wsum[0] + wsum[1] + wsum[2] + wsum[3];
        atomicAdd(ws, b);
    }
}

__global__ void ql_finalize(const double* __restrict__ ws, float* __restrict__ out, long rows) {
    out[0] = (float)(ws[0] / (double)(rows * 5));
}

extern "C" void kernel_launch(void* const* d_in, const int* in_sizes, int n_in,
                              void* d_out, int out_size, void* d_ws, size_t ws_size,
                              hipStream_t stream) {
    const float* preds = (const float*)d_in[0];
    const float* target = (const float*)d_in[1];
    long rows = (long)in_sizes[0] / 5;

    double* acc = (double*)d_ws;
    hipMemsetAsync(acc, 0, sizeof(double), stream);

    int blocks = (int)((rows + TILE - 1) / TILE);
    ql_main<<<blocks, BLOCK, 0, stream>>>(preds, target, acc, rows);
    ql_finalize<<<1, 1, 0, stream>>>(acc, (float*)d_out, rows);
}

// Round 3
// 157.358 us; speedup vs baseline: 2.0265x; 2.0265x over previous
//
#include <hip/hip_runtime.h>

// QuantileLoss: mean over [ (p0-t0)^2, (p1-t1)^2, (p2-t2)^2, lower, upper ]
//   lower = p3>p2 ? (p4-t2)*4 : (p3>0.95*t2 ? 0 : (p3-0.95*t2)^2)
//   upper = p4<p2 ? (p4-t2)*4 : (p4<1.05*t2 ? 0 : (p4-1.05*t2)^2)
//
// R1/R2 evidence: single-address atomicAdd(double) serialized both rounds
// (~15 ns/block: 4096 blocks=61us, 16384 blocks=205us; L3-warm == cold).
// R3: (a) no atomics — per-block partial sums to distinct ws slots + tiny
// finalize kernel; (b) 1024 blocks grid-striding 16 tiles each with register
// prefetch; (c) wave-private 64-row LDS tiles -> ZERO __syncthreads in the
// hot loop (DS ops are in-order per wave); coalesced float4 staging, odd
// stride (5/3) LDS readback = conflict-free.

#define BLOCK 256
#define NBLK  1024
#define WAVES_PER_BLOCK (BLOCK / 64)

__device__ __forceinline__ float row_loss(float p0, float p1, float p2,
                                          float p3, float p4,
                                          float t0, float t1, float t2) {
    float d0 = p0 - t0, d1 = p1 - t1, d2 = p2 - t2;
    float acc = d0 * d0 + d1 * d1 + d2 * d2;
    float tl = t2 * 0.95f;
    float tu = t2 * 1.05f;
    float pen = (p4 - t2) * 4.0f;
    float dl = p3 - tl;
    float du = p4 - tu;
    float lower = (p3 > p2) ? pen : ((p3 > tl) ? 0.0f : dl * dl);
    float upper = (p4 < p2) ? pen : ((p4 < tu) ? 0.0f : du * du);
    return acc + lower + upper;
}

__global__ __launch_bounds__(BLOCK) void ql_main(const float* __restrict__ preds,
                                                 const float* __restrict__ target,
                                                 double* __restrict__ ws,
                                                 long ntiles) {
    // per-wave region: 80 float4 preds (64 rows x 5) + 48 float4 target (64 x 3)
    __shared__ float4 sbuf[WAVES_PER_BLOCK][128];
    __shared__ double wsum[WAVES_PER_BLOCK];

    const int lane = threadIdx.x & 63;
    const int w = threadIdx.x >> 6;
    const long gwave = (long)blockIdx.x * WAVES_PER_BLOCK + w;
    const long nw = (long)gridDim.x * WAVES_PER_BLOCK;

    const float4* pb4 = (const float4*)preds;
    const float4* tb4 = (const float4*)target;
    float* sp = (float*)&sbuf[w][0];    // 320 floats: preds rows, stride 5
    float* st = (float*)&sbuf[w][80];   // 192 floats: target rows, stride 3

    float acc = 0.0f;
    long t = gwave;
    bool have = t < ntiles;
    float4 r0, r1;
    if (have) {
        r0 = pb4[t * 80 + lane];
        r1 = (lane < 16) ? pb4[t * 80 + 64 + lane] : tb4[t * 48 + (lane - 16)];
    }

    while (have) {
        // stage current tile into this wave's private LDS region (no barrier:
        // DS ops execute in order within a wave)
        sbuf[w][lane] = r0;
        sbuf[w][(lane < 16) ? (64 + lane) : (80 + lane - 16)] = r1;

        // prefetch next tile (global loads in flight across the consume phase)
        long tn = t + nw;
        bool haven = tn < ntiles;
        if (haven) {
            r0 = pb4[tn * 80 + lane];
            r1 = (lane < 16) ? pb4[tn * 80 + 64 + lane] : tb4[tn * 48 + (lane - 16)];
        }

        // consume: one row per lane; stride 5/3 -> conflict-free
        acc += row_loss(sp[5 * lane + 0], sp[5 * lane + 1], sp[5 * lane + 2],
                        sp[5 * lane + 3], sp[5 * lane + 4],
                        st[3 * lane + 0], st[3 * lane + 1], st[3 * lane + 2]);

        t = tn;
        have = haven;
    }

    // wave reduction (double), cross-wave via LDS, one plain store per block
    double dacc = (double)acc;
#pragma unroll
    for (int off = 32; off > 0; off >>= 1)
        dacc += __shfl_down(dacc, off, 64);
    if (lane == 0) wsum[w] = dacc;
    __syncthreads();
    if (threadIdx.x == 0)
        ws[blockIdx.x] = wsum[0] + wsum[1] + wsum[2] + wsum[3];
}

__global__ __launch_bounds__(256) void ql_finalize(const double* __restrict__ ws,
                                                   const float* __restrict__ preds,
                                                   const float* __restrict__ target,
                                                   float* __restrict__ out,
                                                   long rows, long tail_start) {
    __shared__ double wsum[4];
    const int tid = threadIdx.x;

    double d = 0.0;
#pragma unroll
    for (int i = 0; i < NBLK / 256; ++i)
        d += ws[tid + i * 256];

    // leftover rows not covered by full 64-row tiles (none for N=4194304)
    long r = tail_start + tid;
    if (r < rows) {
        const float* p = preds + r * 5;
        const float* tg = target + r * 3;
        d += (double)row_loss(p[0], p[1], p[2], p[3], p[4], tg[0], tg[1], tg[2]);
    }

#pragma unroll
    for (int off = 32; off > 0; off >>= 1)
        d += __shfl_down(d, off, 64);
    int lane = tid & 63, w = tid >> 6;
    if (lane == 0) wsum[w] = d;
    __syncthreads();
    if (tid == 0) {
        double total = wsum[0] + wsum[1] + wsum[2] + wsum[3];
        out[0] = (float)(total / ((double)rows * 5.0));
    }
}

extern "C" void kernel_launch(void* const* d_in, const int* in_sizes, int n_in,
                              void* d_out, int out_size, void* d_ws, size_t ws_size,
                              hipStream_t stream) {
    const float* preds = (const float*)d_in[0];
    const float* target = (const float*)d_in[1];
    long rows = (long)in_sizes[0] / 5;
    long ntiles = rows / 64;            // full 64-row tiles
    long tail_start = ntiles * 64;

    double* partials = (double*)d_ws;   // NBLK doubles = 8 KB

    ql_main<<<NBLK, BLOCK, 0, stream>>>(preds, target, partials, ntiles);
    ql_finalize<<<1, 256, 0, stream>>>(partials, preds, target,
                                       (float*)d_out, rows, tail_start);
}